// Round 7
// baseline (115.208 us; speedup 1.0000x reference)
//
#include <hip/hip_runtime.h>
#include <hip/hip_bf16.h>
#include <stdint.h>

// MB=128, C=2048, P=32, DG=256, DF=256, DOUT=128
using short8  = __attribute__((ext_vector_type(8))) short;
using f32x4   = __attribute__((ext_vector_type(4))) float;
using f32x16  = __attribute__((ext_vector_type(16))) float;
using uint4v  = __attribute__((ext_vector_type(4))) unsigned int;

#define MFMA16(a,b,c) __builtin_amdgcn_mfma_f32_16x16x32_bf16((a),(b),(c),0,0,0)
#define MFMA32(a,b,c) __builtin_amdgcn_mfma_f32_32x32x16_bf16((a),(b),(c),0,0,0)
// 4-bit XOR swizzle on 16B slots within 512B rows (proven: conflicts ~1M, free)
#define SWZ15(row, byteoff) ((byteoff) ^ (((row)&15)<<4))

__device__ inline short f2bf(float f){              // RNE
  unsigned u = __float_as_uint(f);
  u += 0x7fff + ((u>>16)&1);
  return (short)(u>>16);
}
// round-half-up bf16 pair pack: bf(a) | bf(b)<<16  (2 adds + 1 v_perm)
__device__ inline unsigned pack2(float a, float b){
  return __builtin_amdgcn_perm(__float_as_uint(b) + 0x8000u,
                               __float_as_uint(a) + 0x8000u, 0x07060302u);
}

// ---- merged prep: [0,1024) transpose x -> xfrag ; [1024,1632) weights -> frags ----
// xfrag (16x16 B-frag, k_ab): slot (b, ck, mt, kk, l, i): token = mt*16+(l&15),
//   c = ck*256 + kk*32 + (l>>4)*8 + i
// W1 (16x16 A-frag, k_ab): ((ct*64 + kk)*64 + lane)*8 + i, d = ct*16+(l&15)
// W2/3/4 (32x32 A-frag, k_heavy): ((ct*16 + kk)*64 + l)*8 + i,
//   d = ct*32 + (l&31), k = kk*16 + (l>>5)*8 + i   [layout verified by R3 k_ab pass]
// R12: x loads vectorized to dwordx4 (G13; 32 scalar -> 8 vector per thread).
__global__ __launch_bounds__(256) void k_prep(const float* __restrict__ x,
                                              short* __restrict__ xfrag,
                                              const float* __restrict__ Wg1,
                                              const float* __restrict__ Wg2,
                                              const float* __restrict__ Wg3,
                                              const float* __restrict__ Wg4,
                                              short* __restrict__ w1f,
                                              short* __restrict__ w2f,
                                              short* __restrict__ w3f,
                                              short* __restrict__ w4f){
  __shared__ float tile[256][33];
  const int bid = blockIdx.x, t = threadIdx.x;
  if (bid < 1024){
    const int ck = bid & 7, b = bid >> 3;
    const float* xb = x + (size_t)b*2048*32 + (size_t)ck*256*32;
#pragma unroll
    for (int r = 0; r < 8; r++){
      int i4 = r*256 + t;             // float4 index 0..2047
      f32x4 v = *(const f32x4*)(xb + (size_t)i4*4);
      int idx = i4*4;                 // = c_local*32 + p ; 4 elems stay in one row
      int row = idx>>5, col = idx&31; // col in {0,4,...,28}
      tile[row][col+0] = v[0];
      tile[row][col+1] = v[1];
      tile[row][col+2] = v[2];
      tile[row][col+3] = v[3];
    }
    __syncthreads();
    short* ob = xfrag + (size_t)(b*8 + ck)*8192; // [mt][kk][l][i]
#pragma unroll
    for (int i4 = 0; i4 < 4; i4++){
      int s = i4*256 + t;             // slot: (mt, kk, l)
      int mt = s>>9, kk = (s>>6)&7, l = s&63;
      int tok = mt*16 + (l&15);
      int cb = kk*32 + (l>>4)*8;
      short8 o;
#pragma unroll
      for (int j = 0; j < 8; j++) o[j] = f2bf(tile[cb+j][tok]);
      *(short8*)(ob + (size_t)s*8) = o;
    }
  } else {
    int g = (bid - 1024)*256 + t;
    if (g < 32*64*64){
      int l = g & 63, kk = (g>>6) & 63, ct = g>>12;
      int d = ct*16 + (l&15);
      int cbase = kk*32 + (l>>4)*8;
      short* o = w1f + (size_t)g*8;
#pragma unroll
      for (int i = 0; i < 8; i++){
        int c = cbase + i;
        float v = (d < 256) ? Wg1[(size_t)c*256 + d]
                            : Wg1[(size_t)(2048 + c)*256 + (d - 256)];
        o[i] = f2bf(v);
      }
    } else {
      int g2 = g - 32*64*64;          // 0..24575
      int L = g2 / 8192;
      int r = g2 - L*8192;            // ((ct*16+kk)*64+l), ct:0..7, kk:0..15
      int l = r & 63, kk = (r>>6)&15, ct = r>>10;
      const float* W = (L==0) ? Wg2 : (L==1) ? Wg3 : Wg4;
      short* o = ((L==0) ? w2f : (L==1) ? w3f : w4f) + (size_t)r*8;
      int d = ct*32 + (l&31);
      int k0 = kk*16 + (l>>5)*8;
#pragma unroll
      for (int i = 0; i < 8; i++) o[i] = f2bf(W[(size_t)(k0+i)*256 + d]);
    }
  }
}

// ------- AB = x @ [W1a|W1b], pure streaming (no LDS, no syncs), 16x16 -------
// grid (128 b, 8 d-slices of 64), 128 thr (2 waves). Wave = 32 tok x 32 d.
// (R0 form — proven. R8's b-pairing halved TLP and regressed; reverted.)
__global__ __launch_bounds__(128) void k_ab(const short* __restrict__ xfrag,
                                            const short* __restrict__ w1f,
                                            float* __restrict__ AB){
  const int wid = threadIdx.x>>6, l = threadIdx.x&63;
  const int b = blockIdx.x;
  const int ctb = blockIdx.y*4 + wid*2;          // wave owns 2 ct (32 d)
  const int hi = l>>4, lo16 = l&15;
  f32x4 acc[2][2] = {};                          // [mt][dt]
  const short* xb = xfrag + (size_t)b*65536 + (size_t)l*8;
  const short* wb = w1f + (size_t)l*8;
#pragma unroll 1
  for (int ck = 0; ck < 8; ck++){
#pragma unroll
    for (int kk = 0; kk < 8; kk++){
      short8 af0 = *(const short8*)(xb + (size_t)ck*8192 + kk*512);
      short8 af1 = *(const short8*)(xb + (size_t)ck*8192 + 4096 + kk*512);
      short8 wf0 = *(const short8*)(wb + ((size_t)(ctb  )*64 + ck*8 + kk)*512);
      short8 wf1 = *(const short8*)(wb + ((size_t)(ctb+1)*64 + ck*8 + kk)*512);
      acc[0][0] = MFMA16(wf0, af0, acc[0][0]);
      acc[1][0] = MFMA16(wf0, af1, acc[1][0]);
      acc[0][1] = MFMA16(wf1, af0, acc[0][1]);
      acc[1][1] = MFMA16(wf1, af1, acc[1][1]);
    }
  }
#pragma unroll
  for (int mt = 0; mt < 2; mt++){
    int m = b*32 + mt*16 + lo16;
#pragma unroll
    for (int dt = 0; dt < 2; dt++){
      int d0 = (ctb+dt)*16 + hi*4;
      *(f32x4*)(AB + (size_t)m*512 + d0) = acc[mt][dt];
    }
  }
}

// ---------------- heavy fused kernel: hp0 init + 3 layers + token-sum ----------------
// grid (128 b, 8 qg), 512 thr (8 waves). act[128 m][256 d] bf16 SWZ15 = 64 KB.
// R12: R8 config exactly (measured 71.4us, VGPR 112, FETCH 5.7MB) — R11's setprio
// removed (cost ~2us, m190-regime: barrier-lockstepped waves give the scheduler
// nothing to arbitrate). Grid (b=x, qg=y): XCD = wgid%8 = b%8, all 8 qg siblings
// of a batch share one XCD L2 (FETCH 20 -> 5.7MB, proven R8).
// Structural constraint (R6-R11): wf amort 4 needs 128-tok tiles -> 64KB act ->
// 2 blocks/CU; LDS pipe ~50% is the max-pipe; every retile that cuts af duplication
// (R6/R9) or adds register state (R7/R10) regressed. Sharp local optimum.
// C layout (R3-verified): col = token = l&31, row d = (r&3) + 8*(r>>2) + 4*(l>>5).
__global__ __launch_bounds__(512) void k_heavy(const float* __restrict__ AB,
                                               const short* __restrict__ w2f,
                                               const short* __restrict__ w3f,
                                               const short* __restrict__ w4f,
                                               const float* __restrict__ bg1,
                                               const float* __restrict__ bg2,
                                               const float* __restrict__ bg3,
                                               const float* __restrict__ bg4,
                                               float* __restrict__ xgp){
  __shared__ short act[128*256];                 // 64 KB
  const int b = blockIdx.x, qg = blockIdx.y, t = threadIdx.x;
  char* abase = (char*)act;

  // hp0[m][d] = relu(A[b,p,d] + B[b,q,d] + bg1[d]);  m = ql*32+p, q = qg*4+ql
#pragma unroll
  for (int it = 0; it < 8; it++){
    int ch = it*512 + t;                         // 4096 chunks of 8 cols
    int m = ch>>5, c0 = (ch&31)*8;
    int q = qg*4 + (m>>5), p = m&31;
    const float* Ap = AB + (size_t)(b*32+p)*512 + c0;
    const float* Bp = AB + (size_t)(b*32+q)*512 + 256 + c0;
    f32x4 a0 = *(const f32x4*)Ap,       a1 = *(const f32x4*)(Ap+4);
    f32x4 b0 = *(const f32x4*)Bp,       b1 = *(const f32x4*)(Bp+4);
    f32x4 g0 = *(const f32x4*)(bg1+c0), g1 = *(const f32x4*)(bg1+c0+4);
    uint4v w;
    w[0] = pack2(fmaxf(a0[0]+b0[0]+g0[0],0.f), fmaxf(a0[1]+b0[1]+g0[1],0.f));
    w[1] = pack2(fmaxf(a0[2]+b0[2]+g0[2],0.f), fmaxf(a0[3]+b0[3]+g0[3],0.f));
    w[2] = pack2(fmaxf(a1[0]+b1[0]+g1[0],0.f), fmaxf(a1[1]+b1[1]+g1[1],0.f));
    w[3] = pack2(fmaxf(a1[2]+b1[2]+g1[2],0.f), fmaxf(a1[3]+b1[3]+g1[3],0.f));
    *(uint4v*)(abase + SWZ15(m, m*512 + c0*2)) = w;
  }
  __syncthreads();

  const int w = t>>6, l = t&63;
  const int tok = l&31, hi = l>>5;               // C col = token, hi picks d+4
  const short* wfr[3]  = {w2f, w3f, w4f};
  const float* bias[3] = {bg2, bg3, bg4};

#pragma unroll
  for (int L = 0; L < 3; L++){
    const short* wp = wfr[L] + ((size_t)(w*16)*64 + l)*8;   // ct=w; + kk*512 shorts
    f32x16 acc[4];                               // [mt], bias folded into C-in
#pragma unroll
    for (int gq = 0; gq < 4; gq++){
      f32x4 bb = *(const f32x4*)(bias[L] + w*32 + gq*8 + hi*4);
#pragma unroll
      for (int j = 0; j < 4; j++){
        float v = bb[j];
#pragma unroll
        for (int mt = 0; mt < 4; mt++) acc[mt][gq*4+j] = v;
      }
    }
#pragma unroll
    for (int kk = 0; kk < 16; kk++){
      short8 wf = *(const short8*)(wp + (size_t)kk*512);
      short8 af[4];
#pragma unroll
      for (int mt = 0; mt < 4; mt++){
        int m = mt*32 + tok;
        af[mt] = *(const short8*)(abase + SWZ15(m, m*512 + kk*32 + hi*16));
      }
#pragma unroll
      for (int mt = 0; mt < 4; mt++)
        acc[mt] = MFMA32(wf, af[mt], acc[mt]);
    }

    if (L < 2){
      __syncthreads();                           // all reads done before overwrite
#pragma unroll
      for (int mt = 0; mt < 4; mt++){
        int m = mt*32 + tok;
#pragma unroll
        for (int gq = 0; gq < 4; gq++){
          int d0 = w*32 + gq*8 + hi*4;
          unsigned lo2 = pack2(fmaxf(acc[mt][gq*4+0],0.f), fmaxf(acc[mt][gq*4+1],0.f));
          unsigned hi2 = pack2(fmaxf(acc[mt][gq*4+2],0.f), fmaxf(acc[mt][gq*4+3],0.f));
          *(uint2*)(abase + SWZ15(m, m*512 + d0*2)) = make_uint2(lo2, hi2);
        }
      }
      __syncthreads();
    } else {
      // relu (bias in acc), sum over all 128 tokens: 4 mt in regs,
      // then butterfly over the 32 token lanes (bits 0-4; hi untouched).
#pragma unroll
      for (int gq = 0; gq < 4; gq++){
        int d0 = w*32 + gq*8 + hi*4;
        f32x4 s;
#pragma unroll
        for (int j = 0; j < 4; j++){
          float v = fmaxf(acc[0][gq*4+j],0.f) + fmaxf(acc[1][gq*4+j],0.f)
                  + fmaxf(acc[2][gq*4+j],0.f) + fmaxf(acc[3][gq*4+j],0.f);
          s[j] = v;
        }
#pragma unroll
        for (int off = 1; off < 32; off <<= 1){
          s[0] += __shfl_xor(s[0], off);
          s[1] += __shfl_xor(s[1], off);
          s[2] += __shfl_xor(s[2], off);
          s[3] += __shfl_xor(s[3], off);
        }
        if (tok == 0)
          *(f32x4*)(xgp + ((size_t)b*8 + qg)*256 + d0) = s;
      }
    }
  }
}

// ---------------- final tiny MLP, fp32, 512 thr, 2-way c-split ----------------
__global__ __launch_bounds__(512) void k_final(const float* __restrict__ xgp,
                                               const float* __restrict__ Wf1,
                                               const float* __restrict__ bf1,
                                               const float* __restrict__ Wfc2,
                                               const float* __restrict__ bfc2,
                                               const float* __restrict__ Wfc3,
                                               const float* __restrict__ bfc3,
                                               float* __restrict__ out){
  __shared__ float b0[256], b1[256], b2[256], part[2][256], part3[4][128];
  const int b = blockIdx.x, t = threadIdx.x;
  if (t < 256){
    float s = 0.f;
#pragma unroll
    for (int g = 0; g < 8; g++) s += xgp[((size_t)b*8 + g)*256 + t];
    b0[t] = s;
  }
  __syncthreads();
  const int d = t & 255, cg = t >> 8;
  {
    float a = cg ? 0.f : bf1[d];
#pragma unroll 8
    for (int c = cg*128; c < cg*128 + 128; c++) a += b0[c] * Wf1[c*256 + d];
    part[cg][d] = a;
  }
  __syncthreads();
  if (t < 256) b1[t] = fmaxf(part[0][t] + part[1][t], 0.f);
  __syncthreads();
  {
    float a = cg ? 0.f : bfc2[d];
#pragma unroll 8
    for (int c = cg*128; c < cg*128 + 128; c++) a += b1[c] * Wfc2[c*256 + d];
    part[cg][d] = a;
  }
  __syncthreads();
  if (t < 256) b2[t] = fmaxf(part[0][t] + part[1][t], 0.f);
  __syncthreads();
  {
    const int d3 = t & 127, cg3 = t >> 7;
    float o = cg3 ? 0.f : bfc3[d3];
#pragma unroll 8
    for (int c = cg3*64; c < cg3*64 + 64; c++) o += b2[c] * Wfc3[c*128 + d3];
    part3[cg3][d3] = o;
  }
  __syncthreads();
  if (t < 128)
    out[(size_t)b*128 + t] = part3[0][t] + part3[1][t] + part3[2][t] + part3[3][t];
}

extern "C" void kernel_launch(void* const* d_in, const int* in_sizes, int n_in,
                              void* d_out, int out_size, void* d_ws, size_t ws_size,
                              hipStream_t stream){
  const float* x    = (const float*)d_in[0];
  const float* Wg1  = (const float*)d_in[1];
  const float* bg1  = (const float*)d_in[2];
  const float* Wg2  = (const float*)d_in[3];
  const float* bg2  = (const float*)d_in[4];
  const float* Wg3  = (const float*)d_in[5];
  const float* bg3  = (const float*)d_in[6];
  const float* Wg4  = (const float*)d_in[7];
  const float* bg4  = (const float*)d_in[8];
  const float* Wf1  = (const float*)d_in[9];
  const float* bf1  = (const float*)d_in[10];
  const float* Wfc2 = (const float*)d_in[11];
  const float* bfc2 = (const float*)d_in[12];
  const float* Wfc3 = (const float*)d_in[13];
  const float* bfc3 = (const float*)d_in[14];
  float* out = (float*)d_out;

  char* ws = (char*)d_ws;
  short* xfrag = (short*)(ws);                   // 16 MB, dead after k_ab
  short* w1f   = (short*)(ws + 16777216);        // 2 MB, dead after k_ab
  short* w2f   = (short*)(ws + 18874368);        // 128 KB
  short* w3f   = (short*)(ws + 19005440);        // 128 KB
  short* w4f   = (short*)(ws + 19136512);        // 128 KB
  float* AB    = (float*)(ws + 19267584);        // 4096*512 f32 = 8 MB
  float* xgp   = (float*)(ws + 16777216);        // 1 MB, aliases dead w1f

  k_prep<<<1632, 256, 0, stream>>>(x, xfrag, Wg1, Wg2, Wg3, Wg4, w1f, w2f, w3f, w4f);
  k_ab<<<dim3(128,8), 128, 0, stream>>>(xfrag, w1f, AB);
  k_heavy<<<dim3(128,8), 512, 0, stream>>>(AB, w2f, w3f, w4f, bg1, bg2, bg3, bg4, xgp);
  k_final<<<128, 512, 0, stream>>>(xgp, Wf1, bf1, Wfc2, bfc2, Wfc3, bfc3, out);
}

// Round 8
// 113.353 us; speedup vs baseline: 1.0164x; 1.0164x over previous
//
#include <hip/hip_runtime.h>
#include <hip/hip_bf16.h>
#include <stdint.h>

// MB=128, C=2048, P=32, DG=256, DF=256, DOUT=128
using short8  = __attribute__((ext_vector_type(8))) short;
using f32x4   = __attribute__((ext_vector_type(4))) float;
using f32x16  = __attribute__((ext_vector_type(16))) float;
using uint4v  = __attribute__((ext_vector_type(4))) unsigned int;

#define MFMA16(a,b,c) __builtin_amdgcn_mfma_f32_16x16x32_bf16((a),(b),(c),0,0,0)
#define MFMA32(a,b,c) __builtin_amdgcn_mfma_f32_32x32x16_bf16((a),(b),(c),0,0,0)
// 4-bit XOR swizzle on 16B slots within 512B rows (proven: conflicts ~1M, free)
#define SWZ15(row, byteoff) ((byteoff) ^ (((row)&15)<<4))

__device__ inline short f2bf(float f){              // RNE
  unsigned u = __float_as_uint(f);
  u += 0x7fff + ((u>>16)&1);
  return (short)(u>>16);
}
// round-half-up bf16 pair pack: bf(a) | bf(b)<<16  (2 adds + 1 v_perm)
__device__ inline unsigned pack2(float a, float b){
  return __builtin_amdgcn_perm(__float_as_uint(b) + 0x8000u,
                               __float_as_uint(a) + 0x8000u, 0x07060302u);
}

// ---- merged prep: [0,1024) transpose x -> xfrag ; [1024,1632) weights -> frags ----
// R13: R0 scalar-load form restored (R12's dwordx4 variant introduced 4-way
// bank-conflicted scalar LDS stores; measured neutral-at-best within tail noise).
// xfrag (16x16 B-frag, k_ab): slot (b, ck, mt, kk, l, i): token = mt*16+(l&15),
//   c = ck*256 + kk*32 + (l>>4)*8 + i
// W1 (16x16 A-frag, k_ab): ((ct*64 + kk)*64 + lane)*8 + i, d = ct*16+(l&15)
// W2/3/4 (32x32 A-frag, k_heavy): ((ct*16 + kk)*64 + l)*8 + i,
//   d = ct*32 + (l&31), k = kk*16 + (l>>5)*8 + i   [layout verified by R3 k_ab pass]
__global__ __launch_bounds__(256) void k_prep(const float* __restrict__ x,
                                              short* __restrict__ xfrag,
                                              const float* __restrict__ Wg1,
                                              const float* __restrict__ Wg2,
                                              const float* __restrict__ Wg3,
                                              const float* __restrict__ Wg4,
                                              short* __restrict__ w1f,
                                              short* __restrict__ w2f,
                                              short* __restrict__ w3f,
                                              short* __restrict__ w4f){
  __shared__ float tile[256][33];
  const int bid = blockIdx.x, t = threadIdx.x;
  if (bid < 1024){
    const int ck = bid & 7, b = bid >> 3;
    const float* xb = x + (size_t)b*2048*32 + (size_t)ck*256*32;
#pragma unroll
    for (int r = 0; r < 32; r++){
      int idx = r*256 + t;            // = c_local*32 + p
      tile[idx>>5][idx&31] = xb[idx];
    }
    __syncthreads();
    short* ob = xfrag + (size_t)(b*8 + ck)*8192; // [mt][kk][l][i]
#pragma unroll
    for (int i4 = 0; i4 < 4; i4++){
      int s = i4*256 + t;             // slot: (mt, kk, l)
      int mt = s>>9, kk = (s>>6)&7, l = s&63;
      int tok = mt*16 + (l&15);
      int cb = kk*32 + (l>>4)*8;
      short8 o;
#pragma unroll
      for (int j = 0; j < 8; j++) o[j] = f2bf(tile[cb+j][tok]);
      *(short8*)(ob + (size_t)s*8) = o;
    }
  } else {
    int g = (bid - 1024)*256 + t;
    if (g < 32*64*64){
      int l = g & 63, kk = (g>>6) & 63, ct = g>>12;
      int d = ct*16 + (l&15);
      int cbase = kk*32 + (l>>4)*8;
      short* o = w1f + (size_t)g*8;
#pragma unroll
      for (int i = 0; i < 8; i++){
        int c = cbase + i;
        float v = (d < 256) ? Wg1[(size_t)c*256 + d]
                            : Wg1[(size_t)(2048 + c)*256 + (d - 256)];
        o[i] = f2bf(v);
      }
    } else {
      int g2 = g - 32*64*64;          // 0..24575
      int L = g2 / 8192;
      int r = g2 - L*8192;            // ((ct*16+kk)*64+l), ct:0..7, kk:0..15
      int l = r & 63, kk = (r>>6)&15, ct = r>>10;
      const float* W = (L==0) ? Wg2 : (L==1) ? Wg3 : Wg4;
      short* o = ((L==0) ? w2f : (L==1) ? w3f : w4f) + (size_t)r*8;
      int d = ct*32 + (l&31);
      int k0 = kk*16 + (l>>5)*8;
#pragma unroll
      for (int i = 0; i < 8; i++) o[i] = f2bf(W[(size_t)(k0+i)*256 + d]);
    }
  }
}

// ------- AB = x @ [W1a|W1b], pure streaming (no LDS, no syncs), 16x16 -------
// grid (128 b, 8 d-slices of 64), 128 thr (2 waves). Wave = 32 tok x 32 d.
// (R0 form — proven. R8's b-pairing halved TLP and regressed; reverted.)
__global__ __launch_bounds__(128) void k_ab(const short* __restrict__ xfrag,
                                            const short* __restrict__ w1f,
                                            float* __restrict__ AB){
  const int wid = threadIdx.x>>6, l = threadIdx.x&63;
  const int b = blockIdx.x;
  const int ctb = blockIdx.y*4 + wid*2;          // wave owns 2 ct (32 d)
  const int hi = l>>4, lo16 = l&15;
  f32x4 acc[2][2] = {};                          // [mt][dt]
  const short* xb = xfrag + (size_t)b*65536 + (size_t)l*8;
  const short* wb = w1f + (size_t)l*8;
#pragma unroll 1
  for (int ck = 0; ck < 8; ck++){
#pragma unroll
    for (int kk = 0; kk < 8; kk++){
      short8 af0 = *(const short8*)(xb + (size_t)ck*8192 + kk*512);
      short8 af1 = *(const short8*)(xb + (size_t)ck*8192 + 4096 + kk*512);
      short8 wf0 = *(const short8*)(wb + ((size_t)(ctb  )*64 + ck*8 + kk)*512);
      short8 wf1 = *(const short8*)(wb + ((size_t)(ctb+1)*64 + ck*8 + kk)*512);
      acc[0][0] = MFMA16(wf0, af0, acc[0][0]);
      acc[1][0] = MFMA16(wf0, af1, acc[1][0]);
      acc[0][1] = MFMA16(wf1, af0, acc[0][1]);
      acc[1][1] = MFMA16(wf1, af1, acc[1][1]);
    }
  }
#pragma unroll
  for (int mt = 0; mt < 2; mt++){
    int m = b*32 + mt*16 + lo16;
#pragma unroll
    for (int dt = 0; dt < 2; dt++){
      int d0 = (ctb+dt)*16 + hi*4;
      *(f32x4*)(AB + (size_t)m*512 + d0) = acc[mt][dt];
    }
  }
}

// ---------------- heavy fused kernel: hp0 init + 3 layers + token-sum ----------------
// grid (128 b, 8 qg), 512 thr (8 waves). act[128 m][256 d] bf16 SWZ15 = 64 KB.
// R13: R8/R12 config exactly — fastest measured (71.1-71.6us, VGPR 112, FETCH 5.7MB).
// Grid (b=x, qg=y): XCD = wgid%8 = b%8, all 8 qg siblings of a batch share one XCD
// L2 (FETCH 20 -> 5.7MB, proven R8). No setprio (R11: -2us, m190 lockstep regime).
// Structural constraint (R6-R11): wf amort 4 needs 128-tok tiles -> 64KB act ->
// 2 blocks/CU; every retile cutting af duplication (R6/R9) or adding register
// state (R7/R10) regressed. Sharp local optimum.
// C layout (R3-verified): col = token = l&31, row d = (r&3) + 8*(r>>2) + 4*(l>>5).
__global__ __launch_bounds__(512) void k_heavy(const float* __restrict__ AB,
                                               const short* __restrict__ w2f,
                                               const short* __restrict__ w3f,
                                               const short* __restrict__ w4f,
                                               const float* __restrict__ bg1,
                                               const float* __restrict__ bg2,
                                               const float* __restrict__ bg3,
                                               const float* __restrict__ bg4,
                                               float* __restrict__ xgp){
  __shared__ short act[128*256];                 // 64 KB
  const int b = blockIdx.x, qg = blockIdx.y, t = threadIdx.x;
  char* abase = (char*)act;

  // hp0[m][d] = relu(A[b,p,d] + B[b,q,d] + bg1[d]);  m = ql*32+p, q = qg*4+ql
#pragma unroll
  for (int it = 0; it < 8; it++){
    int ch = it*512 + t;                         // 4096 chunks of 8 cols
    int m = ch>>5, c0 = (ch&31)*8;
    int q = qg*4 + (m>>5), p = m&31;
    const float* Ap = AB + (size_t)(b*32+p)*512 + c0;
    const float* Bp = AB + (size_t)(b*32+q)*512 + 256 + c0;
    f32x4 a0 = *(const f32x4*)Ap,       a1 = *(const f32x4*)(Ap+4);
    f32x4 b0 = *(const f32x4*)Bp,       b1 = *(const f32x4*)(Bp+4);
    f32x4 g0 = *(const f32x4*)(bg1+c0), g1 = *(const f32x4*)(bg1+c0+4);
    uint4v w;
    w[0] = pack2(fmaxf(a0[0]+b0[0]+g0[0],0.f), fmaxf(a0[1]+b0[1]+g0[1],0.f));
    w[1] = pack2(fmaxf(a0[2]+b0[2]+g0[2],0.f), fmaxf(a0[3]+b0[3]+g0[3],0.f));
    w[2] = pack2(fmaxf(a1[0]+b1[0]+g1[0],0.f), fmaxf(a1[1]+b1[1]+g1[1],0.f));
    w[3] = pack2(fmaxf(a1[2]+b1[2]+g1[2],0.f), fmaxf(a1[3]+b1[3]+g1[3],0.f));
    *(uint4v*)(abase + SWZ15(m, m*512 + c0*2)) = w;
  }
  __syncthreads();

  const int w = t>>6, l = t&63;
  const int tok = l&31, hi = l>>5;               // C col = token, hi picks d+4
  const short* wfr[3]  = {w2f, w3f, w4f};
  const float* bias[3] = {bg2, bg3, bg4};

#pragma unroll
  for (int L = 0; L < 3; L++){
    const short* wp = wfr[L] + ((size_t)(w*16)*64 + l)*8;   // ct=w; + kk*512 shorts
    f32x16 acc[4];                               // [mt], bias folded into C-in
#pragma unroll
    for (int gq = 0; gq < 4; gq++){
      f32x4 bb = *(const f32x4*)(bias[L] + w*32 + gq*8 + hi*4);
#pragma unroll
      for (int j = 0; j < 4; j++){
        float v = bb[j];
#pragma unroll
        for (int mt = 0; mt < 4; mt++) acc[mt][gq*4+j] = v;
      }
    }
#pragma unroll
    for (int kk = 0; kk < 16; kk++){
      short8 wf = *(const short8*)(wp + (size_t)kk*512);
      short8 af[4];
#pragma unroll
      for (int mt = 0; mt < 4; mt++){
        int m = mt*32 + tok;
        af[mt] = *(const short8*)(abase + SWZ15(m, m*512 + kk*32 + hi*16));
      }
#pragma unroll
      for (int mt = 0; mt < 4; mt++)
        acc[mt] = MFMA32(wf, af[mt], acc[mt]);
    }

    if (L < 2){
      __syncthreads();                           // all reads done before overwrite
#pragma unroll
      for (int mt = 0; mt < 4; mt++){
        int m = mt*32 + tok;
#pragma unroll
        for (int gq = 0; gq < 4; gq++){
          int d0 = w*32 + gq*8 + hi*4;
          unsigned lo2 = pack2(fmaxf(acc[mt][gq*4+0],0.f), fmaxf(acc[mt][gq*4+1],0.f));
          unsigned hi2 = pack2(fmaxf(acc[mt][gq*4+2],0.f), fmaxf(acc[mt][gq*4+3],0.f));
          *(uint2*)(abase + SWZ15(m, m*512 + d0*2)) = make_uint2(lo2, hi2);
        }
      }
      __syncthreads();
    } else {
      // relu (bias in acc), sum over all 128 tokens: 4 mt in regs,
      // then butterfly over the 32 token lanes (bits 0-4; hi untouched).
#pragma unroll
      for (int gq = 0; gq < 4; gq++){
        int d0 = w*32 + gq*8 + hi*4;
        f32x4 s;
#pragma unroll
        for (int j = 0; j < 4; j++){
          float v = fmaxf(acc[0][gq*4+j],0.f) + fmaxf(acc[1][gq*4+j],0.f)
                  + fmaxf(acc[2][gq*4+j],0.f) + fmaxf(acc[3][gq*4+j],0.f);
          s[j] = v;
        }
#pragma unroll
        for (int off = 1; off < 32; off <<= 1){
          s[0] += __shfl_xor(s[0], off);
          s[1] += __shfl_xor(s[1], off);
          s[2] += __shfl_xor(s[2], off);
          s[3] += __shfl_xor(s[3], off);
        }
        if (tok == 0)
          *(f32x4*)(xgp + ((size_t)b*8 + qg)*256 + d0) = s;
      }
    }
  }
}

// ---------------- final tiny MLP, fp32, 512 thr, 2-way c-split ----------------
__global__ __launch_bounds__(512) void k_final(const float* __restrict__ xgp,
                                               const float* __restrict__ Wf1,
                                               const float* __restrict__ bf1,
                                               const float* __restrict__ Wfc2,
                                               const float* __restrict__ bfc2,
                                               const float* __restrict__ Wfc3,
                                               const float* __restrict__ bfc3,
                                               float* __restrict__ out){
  __shared__ float b0[256], b1[256], b2[256], part[2][256], part3[4][128];
  const int b = blockIdx.x, t = threadIdx.x;
  if (t < 256){
    float s = 0.f;
#pragma unroll
    for (int g = 0; g < 8; g++) s += xgp[((size_t)b*8 + g)*256 + t];
    b0[t] = s;
  }
  __syncthreads();
  const int d = t & 255, cg = t >> 8;
  {
    float a = cg ? 0.f : bf1[d];
#pragma unroll 8
    for (int c = cg*128; c < cg*128 + 128; c++) a += b0[c] * Wf1[c*256 + d];
    part[cg][d] = a;
  }
  __syncthreads();
  if (t < 256) b1[t] = fmaxf(part[0][t] + part[1][t], 0.f);
  __syncthreads();
  {
    float a = cg ? 0.f : bfc2[d];
#pragma unroll 8
    for (int c = cg*128; c < cg*128 + 128; c++) a += b1[c] * Wfc2[c*256 + d];
    part[cg][d] = a;
  }
  __syncthreads();
  if (t < 256) b2[t] = fmaxf(part[0][t] + part[1][t], 0.f);
  __syncthreads();
  {
    const int d3 = t & 127, cg3 = t >> 7;
    float o = cg3 ? 0.f : bfc3[d3];
#pragma unroll 8
    for (int c = cg3*64; c < cg3*64 + 64; c++) o += b2[c] * Wfc3[c*128 + d3];
    part3[cg3][d3] = o;
  }
  __syncthreads();
  if (t < 128)
    out[(size_t)b*128 + t] = part3[0][t] + part3[1][t] + part3[2][t] + part3[3][t];
}

extern "C" void kernel_launch(void* const* d_in, const int* in_sizes, int n_in,
                              void* d_out, int out_size, void* d_ws, size_t ws_size,
                              hipStream_t stream){
  const float* x    = (const float*)d_in[0];
  const float* Wg1  = (const float*)d_in[1];
  const float* bg1  = (const float*)d_in[2];
  const float* Wg2  = (const float*)d_in[3];
  const float* bg2  = (const float*)d_in[4];
  const float* Wg3  = (const float*)d_in[5];
  const float* bg3  = (const float*)d_in[6];
  const float* Wg4  = (const float*)d_in[7];
  const float* bg4  = (const float*)d_in[8];
  const float* Wf1  = (const float*)d_in[9];
  const float* bf1  = (const float*)d_in[10];
  const float* Wfc2 = (const float*)d_in[11];
  const float* bfc2 = (const float*)d_in[12];
  const float* Wfc3 = (const float*)d_in[13];
  const float* bfc3 = (const float*)d_in[14];
  float* out = (float*)d_out;

  char* ws = (char*)d_ws;
  short* xfrag = (short*)(ws);                   // 16 MB, dead after k_ab
  short* w1f   = (short*)(ws + 16777216);        // 2 MB, dead after k_ab
  short* w2f   = (short*)(ws + 18874368);        // 128 KB
  short* w3f   = (short*)(ws + 19005440);        // 128 KB
  short* w4f   = (short*)(ws + 19136512);        // 128 KB
  float* AB    = (float*)(ws + 19267584);        // 4096*512 f32 = 8 MB
  float* xgp   = (float*)(ws + 16777216);        // 1 MB, aliases dead w1f

  k_prep<<<1632, 256, 0, stream>>>(x, xfrag, Wg1, Wg2, Wg3, Wg4, w1f, w2f, w3f, w4f);
  k_ab<<<dim3(128,8), 128, 0, stream>>>(xfrag, w1f, AB);
  k_heavy<<<dim3(128,8), 512, 0, stream>>>(AB, w2f, w3f, w4f, bg1, bg2, bg3, bg4, xgp);
  k_final<<<128, 512, 0, stream>>>(xgp, Wf1, bf1, Wfc2, bfc2, Wfc3, bfc3, out);
}